// Round 8
// baseline (114.637 us; speedup 1.0000x reference)
//
#include <hip/hip_runtime.h>

#define SDIM 65536
#define BDIM 32
#define RDIM 128
#define NDEG 4
#define NCHUNK 512
#define CHUNK_S (SDIM / NCHUNK)   /* 128 s-values per chunk */
#define MTOT (BDIM * SDIM)        /* 2097152 */
#define EPS_BN 1e-5f
#define NSTATB 512                /* k_stats grid */

// ---------------- K1a: per-block partial stats (no atomics, no init needed) ----
__global__ void k_stats(const float* __restrict__ x, float* __restrict__ partial) {
    __shared__ float s_sum[256];
    __shared__ float s_sq[256];
    int tid = threadIdx.x;
    int gid = blockIdx.x * 256 + tid;
    int stride = gridDim.x * 256;
    float sum = 0.f, sq = 0.f;
    const float4* x4 = (const float4*)x;
    for (int i = gid; i < MTOT / 4; i += stride) {
        float4 v = x4[i];
        sum += (v.x + v.y) + (v.z + v.w);
        sq  += (v.x * v.x + v.y * v.y) + (v.z * v.z + v.w * v.w);
    }
    s_sum[tid] = sum; s_sq[tid] = sq;
    __syncthreads();
    for (int off = 128; off > 0; off >>= 1) {
        if (tid < off) { s_sum[tid] += s_sum[tid + off]; s_sq[tid] += s_sq[tid + off]; }
        __syncthreads();
    }
    if (tid == 0) { partial[blockIdx.x * 2] = s_sum[0]; partial[blockIdx.x * 2 + 1] = s_sq[0]; }
}

// ---------------- K1b: finalize stats (1 block) ----------------
__global__ void k_stats_fin(const float* __restrict__ partial, float* __restrict__ stats) {
    __shared__ float s_sum[256];
    __shared__ float s_sq[256];
    int tid = threadIdx.x;
    float sum = partial[tid * 2] + partial[(tid + 256) * 2];
    float sq  = partial[tid * 2 + 1] + partial[(tid + 256) * 2 + 1];
    s_sum[tid] = sum; s_sq[tid] = sq;
    __syncthreads();
    for (int off = 128; off > 0; off >>= 1) {
        if (tid < off) { s_sum[tid] += s_sum[tid + off]; s_sq[tid] += s_sq[tid + off]; }
        __syncthreads();
    }
    if (tid == 0) { stats[0] = s_sum[0]; stats[1] = s_sq[0]; }
}

// ---------------- K2: normalize + transpose -> zT[s][b], LDS tiled ----------------
__global__ void __launch_bounds__(256) k_norm_t(const float* __restrict__ x,
                                                const float* __restrict__ gamma,
                                                const float* __restrict__ bnb,
                                                const float* __restrict__ stats,
                                                float* __restrict__ zT) {
    __shared__ float lds[64][33];   // pad to kill bank conflicts
    int tid = threadIdx.x;
    int s0 = blockIdx.x * 64;
    float mean = stats[0] * (1.f / MTOT);
    float var  = stats[1] * (1.f / MTOT) - mean * mean;
    float istd = rsqrtf(var + EPS_BN);
    float a  = gamma[0] * istd;
    float c0 = bnb[0] - mean * a;

    int sl = tid & 63, bq = tid >> 6;     // load phase: lane along s (coalesced)
#pragma unroll
    for (int k = 0; k < 8; ++k) {
        int b = k * 4 + bq;
        lds[sl][b] = fmaf(a, x[(size_t)b * SDIM + s0 + sl], c0);
    }
    __syncthreads();
    int bl = tid & 31, sq = tid >> 5;     // store phase: lane along b (coalesced)
#pragma unroll
    for (int k = 0; k < 8; ++k) {
        int s = k * 8 + sq;
        zT[(size_t)(s0 + s) * BDIM + bl] = lds[s][bl];
    }
}

// 16 FMA: one z-quad (4 b-values) x one u-quad (4 r-values)
#define FMA16(zz, uu) \
    acc[0][0]=fmaf(zz.x,uu.x,acc[0][0]); acc[0][1]=fmaf(zz.x,uu.y,acc[0][1]); \
    acc[0][2]=fmaf(zz.x,uu.z,acc[0][2]); acc[0][3]=fmaf(zz.x,uu.w,acc[0][3]); \
    acc[1][0]=fmaf(zz.y,uu.x,acc[1][0]); acc[1][1]=fmaf(zz.y,uu.y,acc[1][1]); \
    acc[1][2]=fmaf(zz.y,uu.z,acc[1][2]); acc[1][3]=fmaf(zz.y,uu.w,acc[1][3]); \
    acc[2][0]=fmaf(zz.z,uu.x,acc[2][0]); acc[2][1]=fmaf(zz.z,uu.y,acc[2][1]); \
    acc[2][2]=fmaf(zz.z,uu.z,acc[2][2]); acc[2][3]=fmaf(zz.z,uu.w,acc[2][3]); \
    acc[3][0]=fmaf(zz.w,uu.x,acc[3][0]); acc[3][1]=fmaf(zz.w,uu.y,acc[3][1]); \
    acc[3][2]=fmaf(zz.w,uu.z,acc[3][2]); acc[3][3]=fmaf(zz.w,uu.w,acc[3][3]);

// ---------------- K3: outer-product GEMM, hand-pipelined U loads ----------------
// Block = (chunk, n). Thread tile 4b x 4r, acc[4][4]. Software pipeline with
// NAMED batch registers uA0..uA3 / uB0..uB3 so the compiler cannot serialize
// the load batch (R7 failure: array-indexed batch collapsed to VGPR_Count=36).
__global__ void __launch_bounds__(256) k_gemm_t(const float* __restrict__ zT,
                                                const float* __restrict__ U,
                                                float* __restrict__ t_part) {
    __shared__ float lds_z[CHUNK_S * BDIM];   // 16 KB
    int tid  = threadIdx.x;
    int p    = tid & 31;          // r-quad: r = 4p .. 4p+3
    int o    = tid >> 5;          // b-quad 0..7
    int chunk = blockIdx.x;       // 0..NCHUNK-1
    int n     = blockIdx.y;       // 0..NDEG-1
    int s0 = chunk * CHUNK_S;

    // stage z chunk to LDS (coalesced float4 copy)
    {
        const float4* src4 = (const float4*)(zT + (size_t)s0 * BDIM);
        float4* dst4 = (float4*)lds_z;
#pragma unroll
        for (int i = 0; i < (CHUNK_S * BDIM / 4) / 256; ++i)
            dst4[i * 256 + tid] = src4[i * 256 + tid];
    }
    __syncthreads();

    const float* Up = U + (size_t)n * SDIM * RDIM + (size_t)s0 * RDIM + 4 * p;
    const float4* zq = (const float4*)lds_z;

    float acc[4][4];
#pragma unroll
    for (int j = 0; j < 4; ++j)
#pragma unroll
        for (int k = 0; k < 4; ++k) acc[j][k] = 0.f;

    // prologue: batch A = rows 0..3
    float4 uA0 = *(const float4*)(Up + (size_t)0 * RDIM);
    float4 uA1 = *(const float4*)(Up + (size_t)1 * RDIM);
    float4 uA2 = *(const float4*)(Up + (size_t)2 * RDIM);
    float4 uA3 = *(const float4*)(Up + (size_t)3 * RDIM);

    for (int ss = 0; ss < CHUNK_S - 4; ss += 4) {
        // issue next batch B (rows ss+4..ss+7) — independent of FMAs below
        float4 uB0 = *(const float4*)(Up + (size_t)(ss + 4) * RDIM);
        float4 uB1 = *(const float4*)(Up + (size_t)(ss + 5) * RDIM);
        float4 uB2 = *(const float4*)(Up + (size_t)(ss + 6) * RDIM);
        float4 uB3 = *(const float4*)(Up + (size_t)(ss + 7) * RDIM);
        // z for current batch A (LDS broadcast)
        float4 z0 = zq[(ss + 0) * (BDIM / 4) + o];
        float4 z1 = zq[(ss + 1) * (BDIM / 4) + o];
        float4 z2 = zq[(ss + 2) * (BDIM / 4) + o];
        float4 z3 = zq[(ss + 3) * (BDIM / 4) + o];
        // compute on batch A
        FMA16(z0, uA0)
        FMA16(z1, uA1)
        FMA16(z2, uA2)
        FMA16(z3, uA3)
        // rotate
        uA0 = uB0; uA1 = uB1; uA2 = uB2; uA3 = uB3;
    }
    // epilogue: rows CHUNK_S-4 .. CHUNK_S-1
    {
        int ss = CHUNK_S - 4;
        float4 z0 = zq[(ss + 0) * (BDIM / 4) + o];
        float4 z1 = zq[(ss + 1) * (BDIM / 4) + o];
        float4 z2 = zq[(ss + 2) * (BDIM / 4) + o];
        float4 z3 = zq[(ss + 3) * (BDIM / 4) + o];
        FMA16(z0, uA0)
        FMA16(z1, uA1)
        FMA16(z2, uA2)
        FMA16(z3, uA3)
    }

    float* outp = t_part + ((size_t)n * NCHUNK + chunk) * (BDIM * RDIM);
#pragma unroll
    for (int j = 0; j < 4; ++j) {
        int b = o * 4 + j;
        *(float4*)(outp + b * RDIM + 4 * p) =
            make_float4(acc[j][0], acc[j][1], acc[j][2], acc[j][3]);
    }
}

// ---------------- K4: fused reduce over 512 chunks + Horner -> h[b][r] ----------------
// block: 256 thr = 8 chunk-groups x 32 i-lanes; grid: 128 blocks (32 i each)
__global__ void __launch_bounds__(256) k_reduce_h(const float* __restrict__ t_part,
                                                  float* __restrict__ h) {
    __shared__ float lds[NDEG][8][32];
    int tid = threadIdx.x;
    int il = tid & 31;        // i-lane within block's 32-wide i-slice
    int cg = tid >> 5;        // chunk group 0..7 (64 chunks each)
    int i0 = blockIdx.x * 32;

#pragma unroll
    for (int n = 0; n < NDEG; ++n) {
        float s = 0.f;
#pragma unroll 8
        for (int k = 0; k < 64; ++k) {
            int c = cg * 64 + k;
            s += t_part[(size_t)(n * NCHUNK + c) * (BDIM * RDIM) + i0 + il];
        }
        lds[n][cg][il] = s;
    }
    __syncthreads();
    if (tid < 32) {
        float t[NDEG];
#pragma unroll
        for (int n = 0; n < NDEG; ++n) {
            float s = 0.f;
#pragma unroll
            for (int g = 0; g < 8; ++g) s += lds[n][g][il];
            t[n] = s;
        }
        float hh = t[0];
#pragma unroll
        for (int n = 1; n < NDEG; ++n) hh = fmaf(t[n], hh, hh);
        h[i0 + il] = hh;
    }
}

// ---------------- K5: out[b][s] = beta[s] + sum_r h[b][r]*C[s][r], 8-way b-split ----
__global__ void __launch_bounds__(256) k_out(const float* __restrict__ h,
                                             const float* __restrict__ Cm,
                                             const float* __restrict__ beta,
                                             float* __restrict__ out) {
    int tid = threadIdx.x;
    int s   = (blockIdx.x >> 1) * 64 + (tid & 63);
    // wave-uniform b-group: force scalarization so h reads become s_load
    int bg  = __builtin_amdgcn_readfirstlane((blockIdx.x & 1) * 4 + (tid >> 6));
    int b0  = bg * 4;

    float acc[4] = {0.f, 0.f, 0.f, 0.f};
    const float4* Cr = (const float4*)(Cm + (size_t)s * RDIM);
    const float* hb = h + b0 * RDIM;               // wave-uniform base -> s_load

#pragma unroll 8
    for (int rc = 0; rc < RDIM / 4; ++rc) {
        float4 c = Cr[rc];
#pragma unroll
        for (int j = 0; j < 4; ++j) {
            const float* hr = hb + j * RDIM + rc * 4;
            float a = acc[j];
            a = fmaf(c.x, hr[0], a);
            a = fmaf(c.y, hr[1], a);
            a = fmaf(c.z, hr[2], a);
            a = fmaf(c.w, hr[3], a);
            acc[j] = a;
        }
    }
    float bt = beta[s];
#pragma unroll
    for (int j = 0; j < 4; ++j)
        out[(size_t)(b0 + j) * SDIM + s] = acc[j] + bt;
}

extern "C" void kernel_launch(void* const* d_in, const int* in_sizes, int n_in,
                              void* d_out, int out_size, void* d_ws, size_t ws_size,
                              hipStream_t stream) {
    const float* x     = (const float*)d_in[0];
    const float* U     = (const float*)d_in[1];
    const float* Cm    = (const float*)d_in[2];
    const float* beta  = (const float*)d_in[3];
    const float* gamma = (const float*)d_in[4];
    const float* bnb   = (const float*)d_in[5];
    float* out = (float*)d_out;

    char* ws = (char*)d_ws;
    size_t off = 0;
    float* stats   = (float*)(ws + off); off += 256;
    float* partial = (float*)(ws + off); off += NSTATB * 2 * 4;
    float* zT      = (float*)(ws + off); off += (size_t)BDIM * SDIM * 4;            // 8 MB
    float* t_part  = (float*)(ws + off); off += (size_t)NDEG * NCHUNK * BDIM * RDIM * 4; // 32 MB
    float* h       = (float*)(ws + off); off += (size_t)BDIM * RDIM * 4;            // 16 KB

    k_stats<<<NSTATB, 256, 0, stream>>>(x, partial);
    k_stats_fin<<<1, 256, 0, stream>>>(partial, stats);
    k_norm_t<<<SDIM / 64, 256, 0, stream>>>(x, gamma, bnb, stats, zT);
    dim3 g3(NCHUNK, NDEG);
    k_gemm_t<<<g3, 256, 0, stream>>>(zT, U, t_part);
    k_reduce_h<<<128, 256, 0, stream>>>(t_part, h);
    k_out<<<2048, 256, 0, stream>>>(h, Cm, beta, out);
}

// Round 10
// 107.875 us; speedup vs baseline: 1.0627x; 1.0627x over previous
//
#include <hip/hip_runtime.h>

#define SDIM 65536
#define BDIM 32
#define RDIM 128
#define NDEG 4
#define NCHUNK 512
#define CHUNK_S (SDIM / NCHUNK)   /* 128 s-values per chunk */
#define NSTEP (CHUNK_S / 16)      /* 8 double-buffer steps of 16 rows */
#define MTOT (BDIM * SDIM)        /* 2097152 */
#define EPS_BN 1e-5f
#define NSTATB 512                /* k_stats grid */

typedef float f32x4 __attribute__((ext_vector_type(4)));

// ---------------- K1a: per-block partial stats (no atomics, no init needed) ----
__global__ void k_stats(const float* __restrict__ x, float* __restrict__ partial) {
    __shared__ float s_sum[256];
    __shared__ float s_sq[256];
    int tid = threadIdx.x;
    int gid = blockIdx.x * 256 + tid;
    int stride = gridDim.x * 256;
    float sum = 0.f, sq = 0.f;
    const float4* x4 = (const float4*)x;
    for (int i = gid; i < MTOT / 4; i += stride) {
        float4 v = x4[i];
        sum += (v.x + v.y) + (v.z + v.w);
        sq  += (v.x * v.x + v.y * v.y) + (v.z * v.z + v.w * v.w);
    }
    s_sum[tid] = sum; s_sq[tid] = sq;
    __syncthreads();
    for (int off = 128; off > 0; off >>= 1) {
        if (tid < off) { s_sum[tid] += s_sum[tid + off]; s_sq[tid] += s_sq[tid + off]; }
        __syncthreads();
    }
    if (tid == 0) { partial[blockIdx.x * 2] = s_sum[0]; partial[blockIdx.x * 2 + 1] = s_sq[0]; }
}

// ---------------- K1b: finalize stats (1 block) ----------------
__global__ void k_stats_fin(const float* __restrict__ partial, float* __restrict__ stats) {
    __shared__ float s_sum[256];
    __shared__ float s_sq[256];
    int tid = threadIdx.x;
    float sum = partial[tid * 2] + partial[(tid + 256) * 2];
    float sq  = partial[tid * 2 + 1] + partial[(tid + 256) * 2 + 1];
    s_sum[tid] = sum; s_sq[tid] = sq;
    __syncthreads();
    for (int off = 128; off > 0; off >>= 1) {
        if (tid < off) { s_sum[tid] += s_sum[tid + off]; s_sq[tid] += s_sq[tid + off]; }
        __syncthreads();
    }
    if (tid == 0) { stats[0] = s_sum[0]; stats[1] = s_sq[0]; }
}

// ---------------- K2: normalize + transpose -> zT[s][b], LDS tiled ----------------
__global__ void __launch_bounds__(256) k_norm_t(const float* __restrict__ x,
                                                const float* __restrict__ gamma,
                                                const float* __restrict__ bnb,
                                                const float* __restrict__ stats,
                                                float* __restrict__ zT) {
    __shared__ float lds[64][33];   // pad to kill bank conflicts
    int tid = threadIdx.x;
    int s0 = blockIdx.x * 64;
    float mean = stats[0] * (1.f / MTOT);
    float var  = stats[1] * (1.f / MTOT) - mean * mean;
    float istd = rsqrtf(var + EPS_BN);
    float a  = gamma[0] * istd;
    float c0 = bnb[0] - mean * a;

    int sl = tid & 63, bq = tid >> 6;     // load phase: lane along s (coalesced)
#pragma unroll
    for (int k = 0; k < 8; ++k) {
        int b = k * 4 + bq;
        lds[sl][b] = fmaf(a, x[(size_t)b * SDIM + s0 + sl], c0);
    }
    __syncthreads();
    int bl = tid & 31, sq = tid >> 5;     // store phase: lane along b (coalesced)
#pragma unroll
    for (int k = 0; k < 8; ++k) {
        int s = k * 8 + sq;
        zT[(size_t)(s0 + s) * BDIM + bl] = lds[s][bl];
    }
}

// 16 FMA: one z-quad (4 b-values) x one u-quad (4 r-values)
#define FMA16(zz, uu) \
    acc[0][0]=fmaf((zz).x,(uu).x,acc[0][0]); acc[0][1]=fmaf((zz).x,(uu).y,acc[0][1]); \
    acc[0][2]=fmaf((zz).x,(uu).z,acc[0][2]); acc[0][3]=fmaf((zz).x,(uu).w,acc[0][3]); \
    acc[1][0]=fmaf((zz).y,(uu).x,acc[1][0]); acc[1][1]=fmaf((zz).y,(uu).y,acc[1][1]); \
    acc[1][2]=fmaf((zz).y,(uu).z,acc[1][2]); acc[1][3]=fmaf((zz).y,(uu).w,acc[1][3]); \
    acc[2][0]=fmaf((zz).z,(uu).x,acc[2][0]); acc[2][1]=fmaf((zz).z,(uu).y,acc[2][1]); \
    acc[2][2]=fmaf((zz).z,(uu).z,acc[2][2]); acc[2][3]=fmaf((zz).z,(uu).w,acc[2][3]); \
    acc[3][0]=fmaf((zz).w,(uu).x,acc[3][0]); acc[3][1]=fmaf((zz).w,(uu).y,acc[3][1]); \
    acc[3][2]=fmaf((zz).w,(uu).z,acc[3][2]); acc[3][3]=fmaf((zz).w,(uu).w,acc[3][3]);

// async global->LDS, 16B per lane, compiler-tracked in vmcnt (drained at barriers)
#define GLL(gp, lp) __builtin_amdgcn_global_load_lds( \
    (const __attribute__((address_space(1))) void*)(gp), \
    (__attribute__((address_space(3))) void*)(lp), 16, 0, 0)

// ---------------- K3: outer-product GEMM, global_load_lds double-buffered U ----
// Block = (chunk, n), 4 waves. z chunk (16 KB) staged once; U staged in 16-row
// tiles (8 KB) double-buffered: stage t+1, compute t from LDS, barrier.
// Thread tile 4b x 4r; per row: 2 ds_read_b128 + 16 FMA.
__global__ void __launch_bounds__(256) k_gemm_t(const float* __restrict__ zT,
                                                const float* __restrict__ U,
                                                float* __restrict__ t_part) {
    __shared__ float z_lds[CHUNK_S * BDIM];   // 16 KB
    __shared__ float u_lds[2][16 * RDIM];     // 2 x 8 KB
    int tid  = threadIdx.x;
    int p    = tid & 31;          // r-quad: r = 4p .. 4p+3
    int o    = tid >> 5;          // b-quad 0..7
    int wv   = tid >> 6;          // wave 0..3 (staging role)
    int ln   = tid & 63;
    int chunk = blockIdx.x;       // 0..NCHUNK-1
    int n     = blockIdx.y;       // 0..NDEG-1
    int s0 = chunk * CHUNK_S;

    // stage z chunk to LDS (coalesced float4 copy)
    {
        const float4* src4 = (const float4*)(zT + (size_t)s0 * BDIM);
        float4* dst4 = (float4*)z_lds;
#pragma unroll
        for (int i = 0; i < (CHUNK_S * BDIM / 4) / 256; ++i)
            dst4[i * 256 + tid] = src4[i * 256 + tid];
    }

    const float* Ut = U + (size_t)n * SDIM * RDIM + (size_t)s0 * RDIM;

    // prologue: stage U step 0 (wave wv stages rows 4wv..4wv+3 = 2 KB = 2 calls)
    {
        const float* gp = Ut + (size_t)(4 * wv) * RDIM + ln * 4;
        float* lp = &u_lds[0][4 * wv * RDIM];
        GLL(gp, lp);
        GLL(gp + 256, lp + 256);
    }
    __syncthreads();   // drains z copy + step-0 staging

    float acc[4][4];
#pragma unroll
    for (int j = 0; j < 4; ++j)
#pragma unroll
        for (int k = 0; k < 4; ++k) acc[j][k] = 0.f;

    for (int t = 0; t < NSTEP; ++t) {
        // issue prefetch of step t+1 BEFORE compute on step t
        if (t + 1 < NSTEP) {
            const float* gp = Ut + (size_t)((t + 1) * 16 + 4 * wv) * RDIM + ln * 4;
            float* lp = &u_lds[(t + 1) & 1][4 * wv * RDIM];
            GLL(gp, lp);
            GLL(gp + 256, lp + 256);
        }
        const float* ub = u_lds[t & 1];
        const float* zb = z_lds + (size_t)(t * 16) * BDIM;
#pragma unroll
        for (int rr = 0; rr < 16; ++rr) {
            f32x4 u4 = *(const f32x4*)(ub + rr * RDIM + 4 * p);
            f32x4 z4 = *(const f32x4*)(zb + rr * BDIM + 4 * o);
            FMA16(z4, u4)
        }
        __syncthreads();   // compiler emits vmcnt(0): step t+1 staged; buffers safe
    }

    float* outp = t_part + ((size_t)n * NCHUNK + chunk) * (BDIM * RDIM);
#pragma unroll
    for (int j = 0; j < 4; ++j) {
        int b = o * 4 + j;
        *(float4*)(outp + b * RDIM + 4 * p) =
            make_float4(acc[j][0], acc[j][1], acc[j][2], acc[j][3]);
    }
}

// ---------------- K4: fused reduce over 512 chunks + Horner -> h[b][r] ----------------
__global__ void __launch_bounds__(256) k_reduce_h(const float* __restrict__ t_part,
                                                  float* __restrict__ h) {
    __shared__ float lds[NDEG][8][32];
    int tid = threadIdx.x;
    int il = tid & 31;        // i-lane within block's 32-wide i-slice
    int cg = tid >> 5;        // chunk group 0..7 (64 chunks each)
    int i0 = blockIdx.x * 32;

#pragma unroll
    for (int n = 0; n < NDEG; ++n) {
        float s = 0.f;
#pragma unroll 8
        for (int k = 0; k < 64; ++k) {
            int c = cg * 64 + k;
            s += t_part[(size_t)(n * NCHUNK + c) * (BDIM * RDIM) + i0 + il];
        }
        lds[n][cg][il] = s;
    }
    __syncthreads();
    if (tid < 32) {
        float t[NDEG];
#pragma unroll
        for (int n = 0; n < NDEG; ++n) {
            float s = 0.f;
#pragma unroll
            for (int g = 0; g < 8; ++g) s += lds[n][g][il];
            t[n] = s;
        }
        float hh = t[0];
#pragma unroll
        for (int n = 1; n < NDEG; ++n) hh = fmaf(t[n], hh, hh);
        h[i0 + il] = hh;
    }
}

// ---------------- K5: out[b][s] = beta[s] + sum_r h[b][r]*C[s][r], 8-way b-split ----
__global__ void __launch_bounds__(256) k_out(const float* __restrict__ h,
                                             const float* __restrict__ Cm,
                                             const float* __restrict__ beta,
                                             float* __restrict__ out) {
    int tid = threadIdx.x;
    int s   = (blockIdx.x >> 1) * 64 + (tid & 63);
    int bg  = __builtin_amdgcn_readfirstlane((blockIdx.x & 1) * 4 + (tid >> 6));
    int b0  = bg * 4;

    float acc[4] = {0.f, 0.f, 0.f, 0.f};
    const float4* Cr = (const float4*)(Cm + (size_t)s * RDIM);
    const float* hb = h + b0 * RDIM;               // wave-uniform base -> s_load

#pragma unroll 8
    for (int rc = 0; rc < RDIM / 4; ++rc) {
        float4 c = Cr[rc];
#pragma unroll
        for (int j = 0; j < 4; ++j) {
            const float* hr = hb + j * RDIM + rc * 4;
            float a = acc[j];
            a = fmaf(c.x, hr[0], a);
            a = fmaf(c.y, hr[1], a);
            a = fmaf(c.z, hr[2], a);
            a = fmaf(c.w, hr[3], a);
            acc[j] = a;
        }
    }
    float bt = beta[s];
#pragma unroll
    for (int j = 0; j < 4; ++j)
        out[(size_t)(b0 + j) * SDIM + s] = acc[j] + bt;
}

extern "C" void kernel_launch(void* const* d_in, const int* in_sizes, int n_in,
                              void* d_out, int out_size, void* d_ws, size_t ws_size,
                              hipStream_t stream) {
    const float* x     = (const float*)d_in[0];
    const float* U     = (const float*)d_in[1];
    const float* Cm    = (const float*)d_in[2];
    const float* beta  = (const float*)d_in[3];
    const float* gamma = (const float*)d_in[4];
    const float* bnb   = (const float*)d_in[5];
    float* out = (float*)d_out;

    char* ws = (char*)d_ws;
    size_t off = 0;
    float* stats   = (float*)(ws + off); off += 256;
    float* partial = (float*)(ws + off); off += NSTATB * 2 * 4;
    float* zT      = (float*)(ws + off); off += (size_t)BDIM * SDIM * 4;            // 8 MB
    float* t_part  = (float*)(ws + off); off += (size_t)NDEG * NCHUNK * BDIM * RDIM * 4; // 32 MB
    float* h       = (float*)(ws + off); off += (size_t)BDIM * RDIM * 4;            // 16 KB

    k_stats<<<NSTATB, 256, 0, stream>>>(x, partial);
    k_stats_fin<<<1, 256, 0, stream>>>(partial, stats);
    k_norm_t<<<SDIM / 64, 256, 0, stream>>>(x, gamma, bnb, stats, zT);
    dim3 g3(NCHUNK, NDEG);
    k_gemm_t<<<g3, 256, 0, stream>>>(zT, U, t_part);
    k_reduce_h<<<128, 256, 0, stream>>>(t_part, h);
    k_out<<<2048, 256, 0, stream>>>(h, Cm, beta, out);
}